// Round 1
// baseline (3976.098 us; speedup 1.0000x reference)
//
#include <hip/hip_runtime.h>
#include <math.h>

#define N_NODES 100000
#define N_EDGES 1600000
#define EP (N_EDGES + N_NODES)   // with self loops
#define F_IN 512
#define HD 64                    // H*D = 8*8
#define CC 7

// ---------------- GEMM1: h1[N,64] = x[N,512] @ W1[512,64] ----------------
__global__ __launch_bounds__(256) void gemm1_kernel(const float* __restrict__ x,
                                                    const float* __restrict__ W1,
                                                    float* __restrict__ h1) {
    __shared__ float xs[64][33];   // +1 pad: avoid 4-way bank conflict on column reads
    __shared__ float ws[32][64];
    const int row0 = blockIdx.x * 64;
    const int tid = threadIdx.x;
    const int ty = tid >> 4, tx = tid & 15;
    float c[4][4] = {};
    for (int k0 = 0; k0 < F_IN; k0 += 32) {
        #pragma unroll
        for (int j = 0; j < 8; ++j) {              // x tile 64x32
            int lin = tid + j * 256;
            int r = lin >> 5, kk = lin & 31;
            int row = row0 + r;
            xs[r][kk] = (row < N_NODES) ? x[(size_t)row * F_IN + k0 + kk] : 0.f;
        }
        #pragma unroll
        for (int j = 0; j < 8; ++j) {              // W1 tile 32x64 (contiguous)
            int lin = tid + j * 256;
            int kk = lin >> 6, cc = lin & 63;
            ws[kk][cc] = W1[(k0 + kk) * HD + cc];
        }
        __syncthreads();
        #pragma unroll
        for (int kk = 0; kk < 32; ++kk) {
            float a[4], b[4];
            #pragma unroll
            for (int i = 0; i < 4; ++i) a[i] = xs[ty * 4 + i][kk];
            #pragma unroll
            for (int j = 0; j < 4; ++j) b[j] = ws[kk][tx * 4 + j];
            #pragma unroll
            for (int i = 0; i < 4; ++i)
                #pragma unroll
                for (int j = 0; j < 4; ++j) c[i][j] += a[i] * b[j];
        }
        __syncthreads();
    }
    #pragma unroll
    for (int i = 0; i < 4; ++i) {
        int row = row0 + ty * 4 + i;
        if (row < N_NODES) {
            #pragma unroll
            for (int j = 0; j < 4; ++j)
                h1[(size_t)row * HD + tx * 4 + j] = c[i][j];
        }
    }
}

// ------------- per-node attention halves, layer 1: [N,8] each -------------
__global__ void att1_kernel(const float* __restrict__ h1,
                            const float* __restrict__ a1s, const float* __restrict__ a1d,
                            float* __restrict__ als, float* __restrict__ ald) {
    int tid = blockIdx.x * blockDim.x + threadIdx.x;
    if (tid >= N_NODES * 8) return;
    int n = tid >> 3, h = tid & 7;
    const float* hp = h1 + (size_t)n * HD + h * 8;
    const float* as = a1s + h * 8;
    const float* ad = a1d + h * 8;
    float s = 0.f, d = 0.f;
    #pragma unroll
    for (int k = 0; k < 8; ++k) { float v = hp[k]; s += v * as[k]; d += v * ad[k]; }
    als[tid] = s; ald[tid] = d;
}

// ------- edge pass 1: p = exp(leaky(al_s[s]+al_d[t])); scatter p, p*h -------
__global__ void edge1_kernel(const int* __restrict__ ei,
                             const float* __restrict__ als, const float* __restrict__ ald,
                             const float* __restrict__ h1,
                             float* __restrict__ z1, float* __restrict__ acc1) {
    int gid = blockIdx.x * blockDim.x + threadIdx.x;
    if (gid >= EP * 8) return;
    int i = gid >> 3, h = gid & 7;
    int s, t;
    if (i < N_EDGES) { s = ei[i]; t = ei[N_EDGES + i]; }
    else             { s = t = i - N_EDGES; }
    float e = als[s * 8 + h] + ald[t * 8 + h];
    e = (e >= 0.f) ? e : 0.2f * e;                 // leaky_relu 0.2
    float p = __expf(e);                            // logits are tiny; max-shift unnecessary
    atomicAdd(&z1[t * 8 + h], p);
    const float* hp = h1 + (size_t)s * HD + h * 8;
    float* ap = acc1 + (size_t)t * HD + h * 8;
    #pragma unroll
    for (int d = 0; d < 8; ++d) atomicAdd(&ap[d], p * hp[d]);
}

// ----------- epilogue 1: h2 = elu(acc1/z1 + b1), written over h1 -----------
__global__ void epi1_kernel(const float* __restrict__ acc1, const float* __restrict__ z1,
                            const float* __restrict__ b1, float* __restrict__ h2) {
    int tid = blockIdx.x * blockDim.x + threadIdx.x;
    if (tid >= N_NODES * HD) return;
    int n = tid >> 6, j = tid & 63;
    float v = acc1[tid] / z1[n * 8 + (j >> 3)] + b1[j];
    h2[tid] = (v > 0.f) ? v : (__expf(v) - 1.f);
}

// -------- GEMM2 + attention halves layer 2: g2[N,7], al2s/al2d[N] ---------
__global__ void gemm2_kernel(const float* __restrict__ h2, const float* __restrict__ W2,
                             const float* __restrict__ a2s, const float* __restrict__ a2d,
                             float* __restrict__ g2, float* __restrict__ al2s,
                             float* __restrict__ al2d) {
    int n = blockIdx.x * blockDim.x + threadIdx.x;
    if (n >= N_NODES) return;
    float g[CC] = {};
    const float* hp = h2 + (size_t)n * HD;
    for (int j = 0; j < HD; ++j) {
        float v = hp[j];
        #pragma unroll
        for (int c = 0; c < CC; ++c) g[c] += v * W2[j * CC + c];
    }
    float s = 0.f, d = 0.f;
    #pragma unroll
    for (int c = 0; c < CC; ++c) { g2[n * 8 + c] = g[c]; s += g[c] * a2s[c]; d += g[c] * a2d[c]; }
    al2s[n] = s; al2d[n] = d;
}

// --------------------------- edge pass 2 ----------------------------------
__global__ void edge2_kernel(const int* __restrict__ ei,
                             const float* __restrict__ al2s, const float* __restrict__ al2d,
                             const float* __restrict__ g2,
                             float* __restrict__ z2, float* __restrict__ acc2) {
    int i = blockIdx.x * blockDim.x + threadIdx.x;
    if (i >= EP) return;
    int s, t;
    if (i < N_EDGES) { s = ei[i]; t = ei[N_EDGES + i]; }
    else             { s = t = i - N_EDGES; }
    float e = al2s[s] + al2d[t];
    e = (e >= 0.f) ? e : 0.2f * e;
    float p = __expf(e);
    atomicAdd(&z2[t], p);
    const float* gp = g2 + (size_t)s * 8;
    float* ap = acc2 + (size_t)t * CC;
    #pragma unroll
    for (int c = 0; c < CC; ++c) atomicAdd(&ap[c], p * gp[c]);
}

// ------------- epilogue 2: log_softmax(acc2/z2 + b2) -> d_out --------------
__global__ void out_kernel(const float* __restrict__ acc2, const float* __restrict__ z2,
                           const float* __restrict__ b2, float* __restrict__ out) {
    int n = blockIdx.x * blockDim.x + threadIdx.x;
    if (n >= N_NODES) return;
    float o[CC];
    float zi = 1.f / z2[n];
    float m = -1e30f;
    #pragma unroll
    for (int c = 0; c < CC; ++c) { o[c] = acc2[n * CC + c] * zi + b2[c]; m = fmaxf(m, o[c]); }
    float sum = 0.f;
    #pragma unroll
    for (int c = 0; c < CC; ++c) sum += __expf(o[c] - m);
    float lse = m + __logf(sum);
    #pragma unroll
    for (int c = 0; c < CC; ++c) out[n * CC + c] = o[c] - lse;
}

extern "C" void kernel_launch(void* const* d_in, const int* in_sizes, int n_in,
                              void* d_out, int out_size, void* d_ws, size_t ws_size,
                              hipStream_t stream) {
    const float* x   = (const float*)d_in[0];
    const int*   ei  = (const int*)d_in[1];    // [2,E] int32
    const float* W1  = (const float*)d_in[2];
    const float* a1s = (const float*)d_in[3];
    const float* a1d = (const float*)d_in[4];
    const float* b1  = (const float*)d_in[5];
    const float* W2  = (const float*)d_in[6];
    const float* a2s = (const float*)d_in[7];
    const float* a2d = (const float*)d_in[8];
    const float* b2  = (const float*)d_in[9];
    float* out = (float*)d_out;

    // workspace layout (floats): h1[N*64] | al1s[N*8] | al1d[N*8] | z1[N*8] | acc1[N*64]
    float* ws   = (float*)d_ws;
    float* h1   = ws;
    float* al1s = h1 + (size_t)N_NODES * HD;
    float* al1d = al1s + (size_t)N_NODES * 8;
    float* z1   = al1d + (size_t)N_NODES * 8;
    float* acc1 = z1 + (size_t)N_NODES * 8;
    // layer-2 reuse (after their layer-1 holders are dead):
    float* g2   = al1s;               // [N,8] (7 used)
    float* al2s = al1d;               // [N]
    float* al2d = al1d + N_NODES;     // [N]
    float* z2   = z1;                 // [N]
    float* acc2 = acc1;               // [N,7]

    // zero z1+acc1 (adjacent) in one shot
    hipMemsetAsync(z1, 0, (size_t)N_NODES * (8 + HD) * sizeof(float), stream);

    gemm1_kernel<<<(N_NODES + 63) / 64, 256, 0, stream>>>(x, W1, h1);
    att1_kernel<<<(N_NODES * 8 + 255) / 256, 256, 0, stream>>>(h1, a1s, a1d, al1s, al1d);
    edge1_kernel<<<(EP * 8 + 255) / 256, 256, 0, stream>>>(ei, al1s, al1d, h1, z1, acc1);
    epi1_kernel<<<(N_NODES * HD + 255) / 256, 256, 0, stream>>>(acc1, z1, b1, h1);
    gemm2_kernel<<<(N_NODES + 255) / 256, 256, 0, stream>>>(h1, W2, a2s, a2d, g2, al2s, al2d);
    // zero z2 and acc2 (now safe: epi1 consumed acc1/z1)
    hipMemsetAsync(z2, 0, (size_t)N_NODES * sizeof(float), stream);
    hipMemsetAsync(acc2, 0, (size_t)N_NODES * CC * sizeof(float), stream);
    edge2_kernel<<<(EP + 255) / 256, 256, 0, stream>>>(ei, al2s, al2d, g2, z2, acc2);
    out_kernel<<<(N_NODES + 255) / 256, 256, 0, stream>>>(acc2, z2, b2, out);
}

// Round 2
// 756.592 us; speedup vs baseline: 5.2553x; 5.2553x over previous
//
#include <hip/hip_runtime.h>
#include <math.h>

#define N_NODES 100000
#define N_EDGES 1600000
#define F_IN 512
#define HD 64                    // H*D = 8*8
#define CC 7

// ---------------- GEMM1: h1[N,64] = x[N,512] @ W1[512,64] ----------------
__global__ __launch_bounds__(256) void gemm1_kernel(const float* __restrict__ x,
                                                    const float* __restrict__ W1,
                                                    float* __restrict__ h1) {
    __shared__ float xs[64][33];
    __shared__ float ws[32][64];
    const int row0 = blockIdx.x * 64;
    const int tid = threadIdx.x;
    const int ty = tid >> 4, tx = tid & 15;
    float c[4][4] = {};
    for (int k0 = 0; k0 < F_IN; k0 += 32) {
        #pragma unroll
        for (int j = 0; j < 8; ++j) {              // x tile 64x32
            int lin = tid + j * 256;
            int r = lin >> 5, kk = lin & 31;
            int row = row0 + r;
            xs[r][kk] = (row < N_NODES) ? x[(size_t)row * F_IN + k0 + kk] : 0.f;
        }
        #pragma unroll
        for (int j = 0; j < 8; ++j) {              // W1 tile 32x64
            int lin = tid + j * 256;
            int kk = lin >> 6, cc = lin & 63;
            ws[kk][cc] = W1[(k0 + kk) * HD + cc];
        }
        __syncthreads();
        #pragma unroll
        for (int kk = 0; kk < 32; ++kk) {
            float a[4], b[4];
            #pragma unroll
            for (int i = 0; i < 4; ++i) a[i] = xs[ty * 4 + i][kk];
            #pragma unroll
            for (int j = 0; j < 4; ++j) b[j] = ws[kk][tx * 4 + j];
            #pragma unroll
            for (int i = 0; i < 4; ++i)
                #pragma unroll
                for (int j = 0; j < 4; ++j) c[i][j] += a[i] * b[j];
        }
        __syncthreads();
    }
    #pragma unroll
    for (int i = 0; i < 4; ++i) {
        int row = row0 + ty * 4 + i;
        if (row < N_NODES) {
            #pragma unroll
            for (int j = 0; j < 4; ++j)
                h1[(size_t)row * HD + tx * 4 + j] = c[i][j];
        }
    }
}

// ------------- per-node attention halves, layer 1: [N,8] each -------------
__global__ void att1_kernel(const float* __restrict__ h1,
                            const float* __restrict__ a1s, const float* __restrict__ a1d,
                            float* __restrict__ als, float* __restrict__ ald) {
    int tid = blockIdx.x * blockDim.x + threadIdx.x;
    if (tid >= N_NODES * 8) return;
    int n = tid >> 3, h = tid & 7;
    const float* hp = h1 + (size_t)n * HD + h * 8;
    const float* as = a1s + h * 8;
    const float* ad = a1d + h * 8;
    float s = 0.f, d = 0.f;
    #pragma unroll
    for (int k = 0; k < 8; ++k) { float v = hp[k]; s += v * as[k]; d += v * ad[k]; }
    als[tid] = s; ald[tid] = d;
}

// ----------------------- CSR build: histogram ------------------------------
__global__ void hist_kernel(const int* __restrict__ ei, int* __restrict__ deg) {
    int i = blockIdx.x * blockDim.x + threadIdx.x;
    if (i >= N_EDGES) return;
    atomicAdd(&deg[ei[N_EDGES + i]], 1);
}

// ------------- CSR build: single-block scan (1024 threads) ----------------
__global__ __launch_bounds__(1024) void scan_kernel(const int* __restrict__ deg,
                                                    int* __restrict__ rowptr,
                                                    int* __restrict__ cursor) {
    __shared__ int sums[1024];
    const int tid = threadIdx.x;
    const int CHUNK = (N_NODES + 1023) / 1024;
    int start = tid * CHUNK;
    int end = start + CHUNK; if (end > N_NODES) end = N_NODES;
    int s = 0;
    for (int i = start; i < end; ++i) s += deg[i];
    sums[tid] = s;
    __syncthreads();
    int mine = s;
    for (int d = 1; d < 1024; d <<= 1) {
        int v = (tid >= d) ? sums[tid - d] : 0;
        __syncthreads();
        sums[tid] += v;
        __syncthreads();
    }
    int off = sums[tid] - mine;   // exclusive prefix
    for (int i = start; i < end; ++i) {
        int d = deg[i];
        rowptr[i] = off; cursor[i] = off;
        off += d;
    }
    if (tid == 1023) rowptr[N_NODES] = off;
}

// ----------------------- CSR build: scatter edges --------------------------
__global__ void scatter_kernel(const int* __restrict__ ei, int* __restrict__ cursor,
                               int* __restrict__ csr_src) {
    int i = blockIdx.x * blockDim.x + threadIdx.x;
    if (i >= N_EDGES) return;
    int t = ei[N_EDGES + i];
    int pos = atomicAdd(&cursor[t], 1);
    csr_src[pos] = ei[i];
}

// ---- gather layer 1: per-dst wave; fused ELU + GEMM2(64->7) + att2 halves ----
__global__ __launch_bounds__(256) void gather1_kernel(
        const int* __restrict__ rowptr, const int* __restrict__ csr_src,
        const float* __restrict__ als, const float* __restrict__ ald,
        const float* __restrict__ h1, const float* __restrict__ b1,
        const float* __restrict__ W2, const float* __restrict__ a2s,
        const float* __restrict__ a2d,
        float* __restrict__ g2, float* __restrict__ al2s, float* __restrict__ al2d) {
    int wid = (blockIdx.x * 256 + threadIdx.x) >> 6;     // one wave per dst node
    if (wid >= N_NODES) return;
    const int lane = threadIdx.x & 63;
    const int h = lane >> 3;
    const int rs = rowptr[wid], re = rowptr[wid + 1];
    const float aldt = ald[wid * 8 + h];
    // self loop
    float e = als[wid * 8 + h] + aldt;
    e = (e >= 0.f) ? e : 0.2f * e;
    float p = __expf(e);
    float acc = p * h1[(size_t)wid * HD + lane];
    float z = p;
    // incoming edges, with next-src prefetch
    int j = rs;
    int s_next = (j < re) ? csr_src[j] : 0;
    while (j < re) {
        int s = s_next;
        ++j;
        if (j < re) s_next = csr_src[j];
        float e2 = als[s * 8 + h] + aldt;
        e2 = (e2 >= 0.f) ? e2 : 0.2f * e2;
        float p2 = __expf(e2);
        acc = fmaf(p2, h1[(size_t)s * HD + lane], acc);
        z += p2;
    }
    // epilogue: alpha-normalize + bias + ELU
    float v = acc / z + b1[lane];
    v = (v > 0.f) ? v : (__expf(v) - 1.f);
    // fused GEMM2: g[c] = sum_j v_j * W2[j][c]  (butterfly over the wave)
    float w[CC];
    #pragma unroll
    for (int c = 0; c < CC; ++c) w[c] = W2[lane * CC + c];
    float g[CC];
    #pragma unroll
    for (int c = 0; c < CC; ++c) {
        float r = v * w[c];
        #pragma unroll
        for (int d = 1; d < 64; d <<= 1) r += __shfl_xor(r, d, 64);
        g[c] = r;
    }
    float s2 = 0.f, d2 = 0.f;
    #pragma unroll
    for (int c = 0; c < CC; ++c) { s2 += g[c] * a2s[c]; d2 += g[c] * a2d[c]; }
    if (lane < CC) g2[(size_t)wid * 8 + lane] = g[lane];
    if (lane == CC) g2[(size_t)wid * 8 + CC] = 0.f;
    if (lane == 8) al2s[wid] = s2;
    if (lane == 9) al2d[wid] = d2;
}

// -------- gather layer 2: 8 lanes per dst node, fused log_softmax ----------
__global__ __launch_bounds__(256) void gather2_kernel(
        const int* __restrict__ rowptr, const int* __restrict__ csr_src,
        const float* __restrict__ al2s, const float* __restrict__ al2d,
        const float* __restrict__ g2, const float* __restrict__ b2,
        float* __restrict__ out) {
    int gid = blockIdx.x * 256 + threadIdx.x;
    int n = gid >> 3, c = gid & 7;
    if (n >= N_NODES) return;
    const int rs = rowptr[n], re = rowptr[n + 1];
    const float adn = al2d[n];
    float e = al2s[n] + adn;
    e = (e >= 0.f) ? e : 0.2f * e;
    float p = __expf(e);
    float acc = p * g2[(size_t)n * 8 + c];
    float z = p;
    int j = rs;
    int s_next = (j < re) ? csr_src[j] : 0;
    while (j < re) {
        int s = s_next;
        ++j;
        if (j < re) s_next = csr_src[j];
        float e2 = al2s[s] + adn;
        e2 = (e2 >= 0.f) ? e2 : 0.2f * e2;
        float p2 = __expf(e2);
        acc = fmaf(p2, g2[(size_t)s * 8 + c], acc);
        z += p2;
    }
    float o = (c < CC) ? (acc / z + b2[c]) : -1e30f;
    float m = o;
    #pragma unroll
    for (int d = 1; d < 8; d <<= 1) m = fmaxf(m, __shfl_xor(m, d, 8));
    float ex = (c < CC) ? __expf(o - m) : 0.f;
    float sum = ex;
    #pragma unroll
    for (int d = 1; d < 8; d <<= 1) sum += __shfl_xor(sum, d, 8);
    float lse = m + __logf(sum);
    if (c < CC) out[(size_t)n * CC + c] = o - lse;
}

extern "C" void kernel_launch(void* const* d_in, const int* in_sizes, int n_in,
                              void* d_out, int out_size, void* d_ws, size_t ws_size,
                              hipStream_t stream) {
    const float* x   = (const float*)d_in[0];
    const int*   ei  = (const int*)d_in[1];
    const float* W1  = (const float*)d_in[2];
    const float* a1s = (const float*)d_in[3];
    const float* a1d = (const float*)d_in[4];
    const float* b1  = (const float*)d_in[5];
    const float* W2  = (const float*)d_in[6];
    const float* a2s = (const float*)d_in[7];
    const float* a2d = (const float*)d_in[8];
    const float* b2  = (const float*)d_in[9];
    float* out = (float*)d_out;

    // workspace layout
    float* h1   = (float*)d_ws;                                  // N*64
    float* al1s = h1 + (size_t)N_NODES * HD;                     // N*8
    float* al1d = al1s + (size_t)N_NODES * 8;                    // N*8
    float* g2   = al1d + (size_t)N_NODES * 8;                    // N*8
    float* al2s = g2 + (size_t)N_NODES * 8;                      // N
    float* al2d = al2s + N_NODES;                                // N
    int* rowptr = (int*)(al2d + N_NODES);                        // N+1
    int* cursor = rowptr + (N_NODES + 1);                        // N
    int* deg    = cursor + N_NODES;                              // N
    int* csr_src= deg + N_NODES;                                 // E

    hipMemsetAsync(deg, 0, (size_t)N_NODES * sizeof(int), stream);
    hist_kernel<<<(N_EDGES + 255) / 256, 256, 0, stream>>>(ei, deg);
    scan_kernel<<<1, 1024, 0, stream>>>(deg, rowptr, cursor);
    scatter_kernel<<<(N_EDGES + 255) / 256, 256, 0, stream>>>(ei, cursor, csr_src);

    gemm1_kernel<<<(N_NODES + 63) / 64, 256, 0, stream>>>(x, W1, h1);
    att1_kernel<<<(N_NODES * 8 + 255) / 256, 256, 0, stream>>>(h1, a1s, a1d, al1s, al1d);

    gather1_kernel<<<(N_NODES * 64 + 255) / 256, 256, 0, stream>>>(
        rowptr, csr_src, al1s, al1d, h1, b1, W2, a2s, a2d, g2, al2s, al2d);
    gather2_kernel<<<(N_NODES * 8 + 255) / 256, 256, 0, stream>>>(
        rowptr, csr_src, al2s, al2d, g2, b2, out);
}

// Round 3
// 519.842 us; speedup vs baseline: 7.6487x; 1.4554x over previous
//
#include <hip/hip_runtime.h>
#include <math.h>

#define N_NODES 100000
#define N_EDGES 1600000
#define F_IN 512
#define HD 64                    // H*D = 8*8
#define CC 7
#define NB ((N_NODES + 1023) / 1024)   // 98 scan blocks

// ---------------- GEMM1: h1[N,64] = x[N,512] @ W1[512,64] ----------------
__global__ __launch_bounds__(256) void gemm1_kernel(const float* __restrict__ x,
                                                    const float* __restrict__ W1,
                                                    float* __restrict__ h1) {
    __shared__ float xs[64][33];
    __shared__ float ws[32][64];
    const int row0 = blockIdx.x * 64;
    const int tid = threadIdx.x;
    const int ty = tid >> 4, tx = tid & 15;
    float c[4][4] = {};
    for (int k0 = 0; k0 < F_IN; k0 += 32) {
        #pragma unroll
        for (int j = 0; j < 8; ++j) {              // x tile 64x32
            int lin = tid + j * 256;
            int r = lin >> 5, kk = lin & 31;
            int row = row0 + r;
            xs[r][kk] = (row < N_NODES) ? x[(size_t)row * F_IN + k0 + kk] : 0.f;
        }
        #pragma unroll
        for (int j = 0; j < 8; ++j) {              // W1 tile 32x64
            int lin = tid + j * 256;
            int kk = lin >> 6, cc = lin & 63;
            ws[kk][cc] = W1[(k0 + kk) * HD + cc];
        }
        __syncthreads();
        #pragma unroll
        for (int kk = 0; kk < 32; ++kk) {
            float a[4], b[4];
            #pragma unroll
            for (int i = 0; i < 4; ++i) a[i] = xs[ty * 4 + i][kk];
            #pragma unroll
            for (int j = 0; j < 4; ++j) b[j] = ws[kk][tx * 4 + j];
            #pragma unroll
            for (int i = 0; i < 4; ++i)
                #pragma unroll
                for (int j = 0; j < 4; ++j) c[i][j] += a[i] * b[j];
        }
        __syncthreads();
    }
    #pragma unroll
    for (int i = 0; i < 4; ++i) {
        int row = row0 + ty * 4 + i;
        if (row < N_NODES) {
            #pragma unroll
            for (int j = 0; j < 4; ++j)
                h1[(size_t)row * HD + tx * 4 + j] = c[i][j];
        }
    }
}

// ------------- per-node attention halves, layer 1: [N,8] each -------------
__global__ void att1_kernel(const float* __restrict__ h1,
                            const float* __restrict__ a1s, const float* __restrict__ a1d,
                            float* __restrict__ als, float* __restrict__ ald) {
    int tid = blockIdx.x * blockDim.x + threadIdx.x;
    if (tid >= N_NODES * 8) return;
    int n = tid >> 3, h = tid & 7;
    const float* hp = h1 + (size_t)n * HD + h * 8;
    const float* as = a1s + h * 8;
    const float* ad = a1d + h * 8;
    float s = 0.f, d = 0.f;
    #pragma unroll
    for (int k = 0; k < 8; ++k) { float v = hp[k]; s += v * as[k]; d += v * ad[k]; }
    als[tid] = s; ald[tid] = d;
}

// ----------------------- CSR build: histogram ------------------------------
__global__ void hist_kernel(const int* __restrict__ ei, int* __restrict__ deg) {
    int i = blockIdx.x * blockDim.x + threadIdx.x;
    if (i >= N_EDGES) return;
    atomicAdd(&deg[ei[N_EDGES + i]], 1);
}

// ------- hierarchical scan stage 1: per-block exclusive prefix + bsum ------
__global__ __launch_bounds__(1024) void scan1_kernel(const int* __restrict__ deg,
                                                     int* __restrict__ lp,
                                                     int* __restrict__ bsum) {
    __shared__ int wsum[16];
    const int t = threadIdx.x;
    const int idx = blockIdx.x * 1024 + t;
    const int lane = t & 63, w = t >> 6;
    int d = (idx < N_NODES) ? deg[idx] : 0;
    int x = d;
    #pragma unroll
    for (int o = 1; o < 64; o <<= 1) {
        int v = __shfl_up(x, o, 64);
        if (lane >= o) x += v;
    }
    if (lane == 63) wsum[w] = x;
    __syncthreads();
    if (w == 0) {
        int s = (lane < 16) ? wsum[lane] : 0;
        #pragma unroll
        for (int o = 1; o < 16; o <<= 1) {
            int v = __shfl_up(s, o, 64);
            if (lane >= o) s += v;
        }
        if (lane < 16) wsum[lane] = s;
    }
    __syncthreads();
    int woff = (w > 0) ? wsum[w - 1] : 0;
    if (idx < N_NODES) lp[idx] = x - d + woff;         // exclusive within block
    if (t == 1023) bsum[blockIdx.x] = woff + x;        // block total
}

// ----- scan stage 2: one small block scans the 98 block sums ----------------
__global__ __launch_bounds__(128) void scan2_kernel(const int* __restrict__ bsum,
                                                    int* __restrict__ boff,
                                                    int* __restrict__ rowptr) {
    __shared__ int wt[2];
    const int t = threadIdx.x;
    const int lane = t & 63, w = t >> 6;
    int v = (t < NB) ? bsum[t] : 0;
    int x = v;
    #pragma unroll
    for (int o = 1; o < 64; o <<= 1) {
        int u = __shfl_up(x, o, 64);
        if (lane >= o) x += u;
    }
    if (lane == 63) wt[w] = x;
    __syncthreads();
    int off = (w == 1) ? wt[0] : 0;
    int ex = x - v + off;
    if (t < NB) boff[t] = ex;
    if (t == NB - 1) rowptr[N_NODES] = ex + v;
}

// ----- scan stage 3: add block offsets, write rowptr & cursor ---------------
__global__ __launch_bounds__(1024) void scan3_kernel(const int* __restrict__ lp,
                                                     const int* __restrict__ boff,
                                                     int* __restrict__ rowptr,
                                                     int* __restrict__ cursor) {
    int idx = blockIdx.x * 1024 + threadIdx.x;
    if (idx >= N_NODES) return;
    int r = lp[idx] + boff[blockIdx.x];
    rowptr[idx] = r;
    cursor[idx] = r;
}

// ----------------------- CSR build: scatter edges --------------------------
__global__ void scatter_kernel(const int* __restrict__ ei, int* __restrict__ cursor,
                               int* __restrict__ csr_src) {
    int i = blockIdx.x * blockDim.x + threadIdx.x;
    if (i >= N_EDGES) return;
    int t = ei[N_EDGES + i];
    int pos = atomicAdd(&cursor[t], 1);
    csr_src[pos] = ei[i];
}

// ---- gather layer 1: per-dst wave; fused ELU + GEMM2(64->7) + att2 halves ----
__global__ __launch_bounds__(256) void gather1_kernel(
        const int* __restrict__ rowptr, const int* __restrict__ csr_src,
        const float* __restrict__ als, const float* __restrict__ ald,
        const float* __restrict__ h1, const float* __restrict__ b1,
        const float* __restrict__ W2, const float* __restrict__ a2s,
        const float* __restrict__ a2d,
        float* __restrict__ g2, float* __restrict__ al2s, float* __restrict__ al2d) {
    int wid = (blockIdx.x * 256 + threadIdx.x) >> 6;     // one wave per dst node
    if (wid >= N_NODES) return;
    const int lane = threadIdx.x & 63;
    const int h = lane >> 3;
    const int rs = rowptr[wid], re = rowptr[wid + 1];
    const float aldt = ald[wid * 8 + h];
    // self loop
    float e = als[wid * 8 + h] + aldt;
    e = (e >= 0.f) ? e : 0.2f * e;
    float p = __expf(e);
    float acc = p * h1[(size_t)wid * HD + lane];
    float z = p;
    // incoming edges, with next-src prefetch
    int j = rs;
    int s_next = (j < re) ? csr_src[j] : 0;
    while (j < re) {
        int s = s_next;
        ++j;
        if (j < re) s_next = csr_src[j];
        float e2 = als[s * 8 + h] + aldt;
        e2 = (e2 >= 0.f) ? e2 : 0.2f * e2;
        float p2 = __expf(e2);
        acc = fmaf(p2, h1[(size_t)s * HD + lane], acc);
        z += p2;
    }
    // epilogue: alpha-normalize + bias + ELU
    float v = acc / z + b1[lane];
    v = (v > 0.f) ? v : (__expf(v) - 1.f);
    // fused GEMM2: g[c] = sum_j v_j * W2[j][c]  (butterfly over the wave)
    float w[CC];
    #pragma unroll
    for (int c = 0; c < CC; ++c) w[c] = W2[lane * CC + c];
    float g[CC];
    #pragma unroll
    for (int c = 0; c < CC; ++c) {
        float r = v * w[c];
        #pragma unroll
        for (int d = 1; d < 64; d <<= 1) r += __shfl_xor(r, d, 64);
        g[c] = r;
    }
    float s2 = 0.f, d2 = 0.f;
    #pragma unroll
    for (int c = 0; c < CC; ++c) { s2 += g[c] * a2s[c]; d2 += g[c] * a2d[c]; }
    if (lane < CC) g2[(size_t)wid * 8 + lane] = g[lane];
    if (lane == CC) g2[(size_t)wid * 8 + CC] = 0.f;
    if (lane == 8) al2s[wid] = s2;
    if (lane == 9) al2d[wid] = d2;
}

// -------- gather layer 2: 8 lanes per dst node, fused log_softmax ----------
__global__ __launch_bounds__(256) void gather2_kernel(
        const int* __restrict__ rowptr, const int* __restrict__ csr_src,
        const float* __restrict__ al2s, const float* __restrict__ al2d,
        const float* __restrict__ g2, const float* __restrict__ b2,
        float* __restrict__ out) {
    int gid = blockIdx.x * 256 + threadIdx.x;
    int n = gid >> 3, c = gid & 7;
    if (n >= N_NODES) return;
    const int rs = rowptr[n], re = rowptr[n + 1];
    const float adn = al2d[n];
    float e = al2s[n] + adn;
    e = (e >= 0.f) ? e : 0.2f * e;
    float p = __expf(e);
    float acc = p * g2[(size_t)n * 8 + c];
    float z = p;
    int j = rs;
    int s_next = (j < re) ? csr_src[j] : 0;
    while (j < re) {
        int s = s_next;
        ++j;
        if (j < re) s_next = csr_src[j];
        float e2 = al2s[s] + adn;
        e2 = (e2 >= 0.f) ? e2 : 0.2f * e2;
        float p2 = __expf(e2);
        acc = fmaf(p2, g2[(size_t)s * 8 + c], acc);
        z += p2;
    }
    float o = (c < CC) ? (acc / z + b2[c]) : -1e30f;
    float m = o;
    #pragma unroll
    for (int d = 1; d < 8; d <<= 1) m = fmaxf(m, __shfl_xor(m, d, 8));
    float ex = (c < CC) ? __expf(o - m) : 0.f;
    float sum = ex;
    #pragma unroll
    for (int d = 1; d < 8; d <<= 1) sum += __shfl_xor(sum, d, 8);
    float lse = m + __logf(sum);
    if (c < CC) out[(size_t)n * CC + c] = o - lse;
}

extern "C" void kernel_launch(void* const* d_in, const int* in_sizes, int n_in,
                              void* d_out, int out_size, void* d_ws, size_t ws_size,
                              hipStream_t stream) {
    const float* x   = (const float*)d_in[0];
    const int*   ei  = (const int*)d_in[1];
    const float* W1  = (const float*)d_in[2];
    const float* a1s = (const float*)d_in[3];
    const float* a1d = (const float*)d_in[4];
    const float* b1  = (const float*)d_in[5];
    const float* W2  = (const float*)d_in[6];
    const float* a2s = (const float*)d_in[7];
    const float* a2d = (const float*)d_in[8];
    const float* b2  = (const float*)d_in[9];
    float* out = (float*)d_out;

    // workspace layout
    float* h1   = (float*)d_ws;                                  // N*64
    float* al1s = h1 + (size_t)N_NODES * HD;                     // N*8
    float* al1d = al1s + (size_t)N_NODES * 8;                    // N*8
    float* g2   = al1d + (size_t)N_NODES * 8;                    // N*8
    float* al2s = g2 + (size_t)N_NODES * 8;                      // N
    float* al2d = al2s + N_NODES;                                // N
    int* rowptr = (int*)(al2d + N_NODES);                        // N+1
    int* cursor = rowptr + (N_NODES + 1);                        // N
    int* deg    = cursor + N_NODES;                              // N
    int* csr_src= deg + N_NODES;                                 // E
    int* lp     = csr_src + N_EDGES;                             // N
    int* bsum   = lp + N_NODES;                                  // NB
    int* boff   = bsum + NB;                                     // NB

    hipMemsetAsync(deg, 0, (size_t)N_NODES * sizeof(int), stream);
    hist_kernel<<<(N_EDGES + 255) / 256, 256, 0, stream>>>(ei, deg);
    scan1_kernel<<<NB, 1024, 0, stream>>>(deg, lp, bsum);
    scan2_kernel<<<1, 128, 0, stream>>>(bsum, boff, rowptr);
    scan3_kernel<<<NB, 1024, 0, stream>>>(lp, boff, rowptr, cursor);
    scatter_kernel<<<(N_EDGES + 255) / 256, 256, 0, stream>>>(ei, cursor, csr_src);

    gemm1_kernel<<<(N_NODES + 63) / 64, 256, 0, stream>>>(x, W1, h1);
    att1_kernel<<<(N_NODES * 8 + 255) / 256, 256, 0, stream>>>(h1, a1s, a1d, al1s, al1d);

    gather1_kernel<<<(N_NODES * 64 + 255) / 256, 256, 0, stream>>>(
        rowptr, csr_src, al1s, al1d, h1, b1, W2, a2s, a2d, g2, al2s, al2d);
    gather2_kernel<<<(N_NODES * 8 + 255) / 256, 256, 0, stream>>>(
        rowptr, csr_src, al2s, al2d, g2, b2, out);
}

// Round 4
// 409.515 us; speedup vs baseline: 9.7093x; 1.2694x over previous
//
#include <hip/hip_runtime.h>
#include <math.h>

#define N_NODES 100000
#define N_EDGES 1600000
#define F_IN 512
#define HD 64                    // H*D = 8*8
#define CC 7
#define NB ((N_NODES + 1023) / 1024)   // 98 scan blocks
#define NKT (F_IN / 32)                // 16 K-steps for MFMA GEMM1

typedef __attribute__((ext_vector_type(8))) short short8;
typedef __attribute__((ext_vector_type(4))) float f32x4;

// float -> bf16 bits, round-to-nearest-even
__device__ inline unsigned short f2bf(float f) {
    union { float f; unsigned u; } v; v.f = f;
    unsigned u = v.u;
    return (unsigned short)((u + 0x7fffu + ((u >> 16) & 1u)) >> 16);
}

// ---- W1 -> bf16 in exact B-fragment order: wf[kt][ct][lane][8] ----
// B frag (16x16x32): col = lane&15, k = (lane>>4)*8 + j
__global__ void w1prep_kernel(const float* __restrict__ W1,
                              unsigned short* __restrict__ wf) {
    int t = blockIdx.x * 256 + threadIdx.x;       // [0, NKT*4*64)
    if (t >= NKT * 4 * 64) return;
    int lane = t & 63;
    int ct = (t >> 6) & 3;
    int kt = t >> 8;
    int k0 = kt * 32 + (lane >> 4) * 8;
    int col = ct * 16 + (lane & 15);
    unsigned short* dst = wf + (size_t)t * 8;
    #pragma unroll
    for (int j = 0; j < 8; ++j) dst[j] = f2bf(W1[(k0 + j) * HD + col]);
}

// ---------------- GEMM1 (MFMA, no LDS): h1[N,64] = x @ W1 ----------------
__global__ __launch_bounds__(256) void gemm1_kernel(const float* __restrict__ x,
                                                    const unsigned short* __restrict__ wf,
                                                    float* __restrict__ h1) {
    const int wave = threadIdx.x >> 6;
    const int lane = threadIdx.x & 63;
    int arow = blockIdx.x * 64 + wave * 16 + (lane & 15);
    if (arow >= N_NODES) arow = N_NODES - 1;       // clamp for load only
    const float* xp = x + (size_t)arow * F_IN + (lane >> 4) * 8;
    const short8* wp = (const short8*)wf;

    f32x4 acc[4] = {};
    #pragma unroll 4
    for (int kt = 0; kt < NKT; ++kt) {
        f32x4 a0 = *(const f32x4*)(xp + kt * 32);
        f32x4 a1 = *(const f32x4*)(xp + kt * 32 + 4);
        union { short8 s; unsigned short u[8]; } af;
        af.u[0] = f2bf(a0.x); af.u[1] = f2bf(a0.y);
        af.u[2] = f2bf(a0.z); af.u[3] = f2bf(a0.w);
        af.u[4] = f2bf(a1.x); af.u[5] = f2bf(a1.y);
        af.u[6] = f2bf(a1.z); af.u[7] = f2bf(a1.w);
        #pragma unroll
        for (int ct = 0; ct < 4; ++ct) {
            short8 bf = wp[kt * 256 + ct * 64 + lane];
            acc[ct] = __builtin_amdgcn_mfma_f32_16x16x32_bf16(af.s, bf, acc[ct], 0, 0, 0);
        }
    }
    // C/D layout: col = lane&15, row = (lane>>4)*4 + r
    const int orow_base = blockIdx.x * 64 + wave * 16 + (lane >> 4) * 4;
    const int ocol = lane & 15;
    #pragma unroll
    for (int ct = 0; ct < 4; ++ct) {
        #pragma unroll
        for (int r = 0; r < 4; ++r) {
            int orow = orow_base + r;
            if (orow < N_NODES)
                h1[(size_t)orow * HD + ct * 16 + ocol] = acc[ct][r];
        }
    }
}

// ------------- per-node attention halves, layer 1: [N,8] each -------------
__global__ void att1_kernel(const float* __restrict__ h1,
                            const float* __restrict__ a1s, const float* __restrict__ a1d,
                            float* __restrict__ als, float* __restrict__ ald) {
    int tid = blockIdx.x * blockDim.x + threadIdx.x;
    if (tid >= N_NODES * 8) return;
    int n = tid >> 3, h = tid & 7;
    const float* hp = h1 + (size_t)n * HD + h * 8;
    const float* as = a1s + h * 8;
    const float* ad = a1d + h * 8;
    float s = 0.f, d = 0.f;
    #pragma unroll
    for (int k = 0; k < 8; ++k) { float v = hp[k]; s += v * as[k]; d += v * ad[k]; }
    als[tid] = s; ald[tid] = d;
}

// ----------------------- CSR build: histogram ------------------------------
__global__ void hist_kernel(const int* __restrict__ ei, int* __restrict__ deg) {
    int i = blockIdx.x * blockDim.x + threadIdx.x;
    if (i >= N_EDGES) return;
    atomicAdd(&deg[ei[N_EDGES + i]], 1);
}

// ------- hierarchical scan stage 1: per-block exclusive prefix + bsum ------
__global__ __launch_bounds__(1024) void scan1_kernel(const int* __restrict__ deg,
                                                     int* __restrict__ lp,
                                                     int* __restrict__ bsum) {
    __shared__ int wsum[16];
    const int t = threadIdx.x;
    const int idx = blockIdx.x * 1024 + t;
    const int lane = t & 63, w = t >> 6;
    int d = (idx < N_NODES) ? deg[idx] : 0;
    int x = d;
    #pragma unroll
    for (int o = 1; o < 64; o <<= 1) {
        int v = __shfl_up(x, o, 64);
        if (lane >= o) x += v;
    }
    if (lane == 63) wsum[w] = x;
    __syncthreads();
    if (w == 0) {
        int s = (lane < 16) ? wsum[lane] : 0;
        #pragma unroll
        for (int o = 1; o < 16; o <<= 1) {
            int v = __shfl_up(s, o, 64);
            if (lane >= o) s += v;
        }
        if (lane < 16) wsum[lane] = s;
    }
    __syncthreads();
    int woff = (w > 0) ? wsum[w - 1] : 0;
    if (idx < N_NODES) lp[idx] = x - d + woff;         // exclusive within block
    if (t == 1023) bsum[blockIdx.x] = woff + x;        // block total
}

// ----- scan stage 2: one small block scans the 98 block sums ----------------
__global__ __launch_bounds__(128) void scan2_kernel(const int* __restrict__ bsum,
                                                    int* __restrict__ boff,
                                                    int* __restrict__ rowptr) {
    __shared__ int wt[2];
    const int t = threadIdx.x;
    const int lane = t & 63, w = t >> 6;
    int v = (t < NB) ? bsum[t] : 0;
    int x = v;
    #pragma unroll
    for (int o = 1; o < 64; o <<= 1) {
        int u = __shfl_up(x, o, 64);
        if (lane >= o) x += u;
    }
    if (lane == 63) wt[w] = x;
    __syncthreads();
    int off = (w == 1) ? wt[0] : 0;
    int ex = x - v + off;
    if (t < NB) boff[t] = ex;
    if (t == NB - 1) rowptr[N_NODES] = ex + v;
}

// ----- scan stage 3: add block offsets, write rowptr & cursor ---------------
__global__ __launch_bounds__(1024) void scan3_kernel(const int* __restrict__ lp,
                                                     const int* __restrict__ boff,
                                                     int* __restrict__ rowptr,
                                                     int* __restrict__ cursor) {
    int idx = blockIdx.x * 1024 + threadIdx.x;
    if (idx >= N_NODES) return;
    int r = lp[idx] + boff[blockIdx.x];
    rowptr[idx] = r;
    cursor[idx] = r;
}

// ----------------------- CSR build: scatter edges --------------------------
__global__ void scatter_kernel(const int* __restrict__ ei, int* __restrict__ cursor,
                               int* __restrict__ csr_src) {
    int i = blockIdx.x * blockDim.x + threadIdx.x;
    if (i >= N_EDGES) return;
    int t = ei[N_EDGES + i];
    int pos = atomicAdd(&cursor[t], 1);
    csr_src[pos] = ei[i];
}

// ---- gather layer 1: per-dst wave; fused ELU + GEMM2(64->7) + att2 halves ----
__global__ __launch_bounds__(256) void gather1_kernel(
        const int* __restrict__ rowptr, const int* __restrict__ csr_src,
        const float* __restrict__ als, const float* __restrict__ ald,
        const float* __restrict__ h1, const float* __restrict__ b1,
        const float* __restrict__ W2, const float* __restrict__ a2s,
        const float* __restrict__ a2d,
        float* __restrict__ g2, float* __restrict__ al2s, float* __restrict__ al2d) {
    int wid = (blockIdx.x * 256 + threadIdx.x) >> 6;     // one wave per dst node
    if (wid >= N_NODES) return;
    const int lane = threadIdx.x & 63;
    const int h = lane >> 3;
    const int rs = rowptr[wid], re = rowptr[wid + 1];
    const float aldt = ald[wid * 8 + h];
    // self loop
    float e = als[wid * 8 + h] + aldt;
    e = (e >= 0.f) ? e : 0.2f * e;
    float p = __expf(e);
    float acc = p * h1[(size_t)wid * HD + lane];
    float z = p;
    // incoming edges, with next-src prefetch
    int j = rs;
    int s_next = (j < re) ? csr_src[j] : 0;
    while (j < re) {
        int s = s_next;
        ++j;
        if (j < re) s_next = csr_src[j];
        float e2 = als[s * 8 + h] + aldt;
        e2 = (e2 >= 0.f) ? e2 : 0.2f * e2;
        float p2 = __expf(e2);
        acc = fmaf(p2, h1[(size_t)s * HD + lane], acc);
        z += p2;
    }
    // epilogue: alpha-normalize + bias + ELU
    float v = acc / z + b1[lane];
    v = (v > 0.f) ? v : (__expf(v) - 1.f);
    // fused GEMM2: g[c] = sum_j v_j * W2[j][c]  (butterfly over the wave)
    float w[CC];
    #pragma unroll
    for (int c = 0; c < CC; ++c) w[c] = W2[lane * CC + c];
    float g[CC];
    #pragma unroll
    for (int c = 0; c < CC; ++c) {
        float r = v * w[c];
        #pragma unroll
        for (int d = 1; d < 64; d <<= 1) r += __shfl_xor(r, d, 64);
        g[c] = r;
    }
    float s2 = 0.f, d2 = 0.f;
    #pragma unroll
    for (int c = 0; c < CC; ++c) { s2 += g[c] * a2s[c]; d2 += g[c] * a2d[c]; }
    if (lane < CC) g2[(size_t)wid * 8 + lane] = g[lane];
    if (lane == CC) g2[(size_t)wid * 8 + CC] = 0.f;
    if (lane == 8) al2s[wid] = s2;
    if (lane == 9) al2d[wid] = d2;
}

// -------- gather layer 2: 8 lanes per dst node, fused log_softmax ----------
__global__ __launch_bounds__(256) void gather2_kernel(
        const int* __restrict__ rowptr, const int* __restrict__ csr_src,
        const float* __restrict__ al2s, const float* __restrict__ al2d,
        const float* __restrict__ g2, const float* __restrict__ b2,
        float* __restrict__ out) {
    int gid = blockIdx.x * 256 + threadIdx.x;
    int n = gid >> 3, c = gid & 7;
    if (n >= N_NODES) return;
    const int rs = rowptr[n], re = rowptr[n + 1];
    const float adn = al2d[n];
    float e = al2s[n] + adn;
    e = (e >= 0.f) ? e : 0.2f * e;
    float p = __expf(e);
    float acc = p * g2[(size_t)n * 8 + c];
    float z = p;
    int j = rs;
    int s_next = (j < re) ? csr_src[j] : 0;
    while (j < re) {
        int s = s_next;
        ++j;
        if (j < re) s_next = csr_src[j];
        float e2 = al2s[s] + adn;
        e2 = (e2 >= 0.f) ? e2 : 0.2f * e2;
        float p2 = __expf(e2);
        acc = fmaf(p2, g2[(size_t)s * 8 + c], acc);
        z += p2;
    }
    float o = (c < CC) ? (acc / z + b2[c]) : -1e30f;
    float m = o;
    #pragma unroll
    for (int d = 1; d < 8; d <<= 1) m = fmaxf(m, __shfl_xor(m, d, 8));
    float ex = (c < CC) ? __expf(o - m) : 0.f;
    float sum = ex;
    #pragma unroll
    for (int d = 1; d < 8; d <<= 1) sum += __shfl_xor(sum, d, 8);
    float lse = m + __logf(sum);
    if (c < CC) out[(size_t)n * CC + c] = o - lse;
}

extern "C" void kernel_launch(void* const* d_in, const int* in_sizes, int n_in,
                              void* d_out, int out_size, void* d_ws, size_t ws_size,
                              hipStream_t stream) {
    const float* x   = (const float*)d_in[0];
    const int*   ei  = (const int*)d_in[1];
    const float* W1  = (const float*)d_in[2];
    const float* a1s = (const float*)d_in[3];
    const float* a1d = (const float*)d_in[4];
    const float* b1  = (const float*)d_in[5];
    const float* W2  = (const float*)d_in[6];
    const float* a2s = (const float*)d_in[7];
    const float* a2d = (const float*)d_in[8];
    const float* b2  = (const float*)d_in[9];
    float* out = (float*)d_out;

    // workspace layout
    float* h1   = (float*)d_ws;                                  // N*64
    float* al1s = h1 + (size_t)N_NODES * HD;                     // N*8
    float* al1d = al1s + (size_t)N_NODES * 8;                    // N*8
    float* g2   = al1d + (size_t)N_NODES * 8;                    // N*8
    float* al2s = g2 + (size_t)N_NODES * 8;                      // N
    float* al2d = al2s + N_NODES;                                // N
    int* rowptr = (int*)(al2d + N_NODES);                        // N+1
    int* cursor = rowptr + (N_NODES + 1);                        // N
    int* deg    = cursor + N_NODES;                              // N
    int* csr_src= deg + N_NODES;                                 // E
    int* lp     = csr_src + N_EDGES;                             // N
    int* bsum   = lp + N_NODES;                                  // NB
    int* boff   = bsum + NB;                                     // NB
    unsigned short* wf = (unsigned short*)(boff + NB);           // NKT*4*64*8 bf16

    hipMemsetAsync(deg, 0, (size_t)N_NODES * sizeof(int), stream);
    w1prep_kernel<<<(NKT * 4 * 64 + 255) / 256, 256, 0, stream>>>(W1, wf);
    hist_kernel<<<(N_EDGES + 255) / 256, 256, 0, stream>>>(ei, deg);
    scan1_kernel<<<NB, 1024, 0, stream>>>(deg, lp, bsum);
    scan2_kernel<<<1, 128, 0, stream>>>(bsum, boff, rowptr);
    scan3_kernel<<<NB, 1024, 0, stream>>>(lp, boff, rowptr, cursor);
    scatter_kernel<<<(N_EDGES + 255) / 256, 256, 0, stream>>>(ei, cursor, csr_src);

    gemm1_kernel<<<(N_NODES + 63) / 64, 256, 0, stream>>>(x, wf, h1);
    att1_kernel<<<(N_NODES * 8 + 255) / 256, 256, 0, stream>>>(h1, a1s, a1d, al1s, al1d);

    gather1_kernel<<<(N_NODES * 64 + 255) / 256, 256, 0, stream>>>(
        rowptr, csr_src, al1s, al1d, h1, b1, W2, a2s, a2d, g2, al2s, al2d);
    gather2_kernel<<<(N_NODES * 8 + 255) / 256, 256, 0, stream>>>(
        rowptr, csr_src, al2s, al2d, g2, b2, out);
}